// Round 13
// baseline (1661.621 us; speedup 1.0000x reference)
//
#include <hip/hip_runtime.h>

// LSTM H=512, B=256, T=256, D_IN=10, C=10. fp32 in/out.
// R13: weights in REGISTERS (272 VGPR/lane, loaded once) - hot loop has ZERO
// LDS traffic (R12 showed L3 B-traffic is not the binder; R9 budget says the
// LDS weight stream ~0.9us + conflicts ~0.45us/step are). B via R9's proven
// batched agent-scope loads (L3 coherence point); barrier/fabric identical to
// R9. 96KB dummy dynamic LDS forces 1 WG/CU structurally regardless of the
// final VGPR count. Numerics identical to R9 (h-hi bf16, W hi+lo, x hi+lo).

#define Hdim 512
#define Bdim 256
#define Tdim 256
#define Kpad 544          // 512 (h) + 32 (x: 10 real + 22 zero)
#define LDS_BYTES 98304   // dummy: occupancy clamp -> exactly 1 WG/CU

typedef __bf16 bf16x8 __attribute__((ext_vector_type(8)));
typedef float f32x4 __attribute__((ext_vector_type(4)));
typedef unsigned long long u64;

__device__ __forceinline__ unsigned short f2bf(float f) {
    union { float f; unsigned u; } x; x.f = f;
    unsigned r = x.u + 0x7FFFu + ((x.u >> 16) & 1u);
    return (unsigned short)(r >> 16);
}
__device__ __forceinline__ float bf2f(unsigned short h) {
    union { unsigned u; float f; } x; x.u = ((unsigned)h) << 16;
    return x.f;
}
__device__ __forceinline__ bf16x8 ld8(const unsigned short* p) {
    return *reinterpret_cast<const bf16x8*>(p);
}
__device__ __forceinline__ u64 ldA(const u64* p) {   // L2-bypass 8B load (L3)
    return __hip_atomic_load(p, __ATOMIC_RELAXED, __HIP_MEMORY_SCOPE_AGENT);
}
// write-through 2B store (agent scope -> lands at L3)
__device__ __forceinline__ void stH(unsigned short* p, unsigned short v) {
    __hip_atomic_store(p, v, __ATOMIC_RELAXED, __HIP_MEMORY_SCOPE_AGENT);
}
__device__ __forceinline__ f32x4 mfma16(bf16x8 a, bf16x8 b, f32x4 c) {
    return __builtin_amdgcn_mfma_f32_16x16x32_bf16(a, b, c, 0, 0, 0);
}
__device__ __forceinline__ bf16x8 pack2(u64 a, u64 b) {
    union { u64 q[2]; bf16x8 v; } u; u.q[0] = a; u.q[1] = b; return u.v;
}
__device__ __forceinline__ float sigm(float x) { return 1.f / (1.f + __expf(-x)); }
__device__ __forceinline__ float tanh_fast(float x) {
    return 2.f / (1.f + __expf(-2.f * x)) - 1.f;
}

// ---------- prep: stacked gate weights -> bf16 hi/lo, row = 4*i + gate ----------
__global__ void k_prep_w(const float* __restrict__ w_gh, const float* __restrict__ w_ih,
                         const float* __restrict__ w_fh, const float* __restrict__ w_oh,
                         const float* __restrict__ w_gx, const float* __restrict__ w_ix,
                         const float* __restrict__ w_fx, const float* __restrict__ w_ox,
                         unsigned short* __restrict__ Whi, unsigned short* __restrict__ Wlo) {
    int idx = blockIdx.x * 256 + threadIdx.x;
    if (idx >= 2048 * Kpad) return;
    int rw = idx / Kpad;
    int k  = idx % Kpad;
    int gate = rw & 3;
    int i = rw >> 2;
    float v = 0.f;
    if (k < 512) {
        const float* wh = (gate == 0) ? w_gh : (gate == 1) ? w_ih : (gate == 2) ? w_fh : w_oh;
        v = wh[i * 512 + k];
    } else if (k < 522) {
        const float* wx = (gate == 0) ? w_gx : (gate == 1) ? w_ix : (gate == 2) ? w_fx : w_ox;
        v = wx[i * 10 + (k - 512)];
    }
    unsigned short hi = f2bf(v);
    unsigned short lo = f2bf(v - bf2f(hi));
    Whi[idx] = hi;
    Wlo[idx] = lo;
}

// ---------- prep: x -> Xhi/Xlo [t][b][32] ----------
__global__ void k_prep_x(const float* __restrict__ x,
                         unsigned short* __restrict__ Xhi, unsigned short* __restrict__ Xlo) {
    int idx = blockIdx.x * 256 + threadIdx.x;
    if (idx >= Tdim * Bdim * 32) return;
    int j = idx & 31;
    int b = (idx >> 5) & 255;
    int t = idx >> 13;
    float v = 0.f;
    if (j < 10) v = x[(b * Tdim + t) * 10 + j];
    unsigned short hi = f2bf(v);
    unsigned short lo = f2bf(v - bf2f(hi));
    Xhi[idx] = hi;
    Xlo[idx] = lo;
}

__global__ void k_zero(float* __restrict__ p) {
    p[blockIdx.x * 256 + threadIdx.x] = 0.f;
}

// ---------- persistent LSTM ----------
// 256 WGs x 256 thr. WG: 64 stacked rows x 32 cols. Waves 2x2: 32 rows x 16 cols.
// Per lane: A rows r0=m0+wm*32+lr and r1=r0+16, hi+lo, ALL K in registers.
__global__ __launch_bounds__(256, 1) void k_persist(
    const unsigned short* __restrict__ Whi, const unsigned short* __restrict__ Wlo,
    const unsigned short* __restrict__ Xhi, const unsigned short* __restrict__ Xlo,
    unsigned short* H0hi, unsigned short* H1hi,
    float* __restrict__ Hf32,
    const float* __restrict__ bg, const float* __restrict__ bi,
    const float* __restrict__ bf_, const float* __restrict__ bo,
    unsigned* flags) {
    extern __shared__ unsigned short lds_dummy[];   // occupancy clamp only
    (void)lds_dummy;

    const int bid = blockIdx.x;
    const int rg  = bid >> 3;                  // row-group id (0..31)
    const int m0  = rg * 64;                   // stacked-row tile base
    const int ct  = bid & 7;                   // column-group id
    const int bn0 = ct * 32;
    const int tid = threadIdx.x;
    const int lane = tid & 63;
    const int wv = tid >> 6;
    const int wm = wv >> 1, wn = wv & 1;
    const int lr = lane & 15, q = lane >> 4;

    // flags: one 64B line per WG: index (ct*32+rg)*16 uints
    unsigned* myflag = flags + (((ct << 5) + rg) << 4);
    unsigned* pollp  = flags + (((ct << 5) + (lane & 31)) << 4);

    const int kq = q * 8;
    const int colc = bn0 + wn * 16 + lr;       // this lane's column
    const int r0 = m0 + wm * 32 + lr;          // A row for acc0 fragments
    const int r1 = r0 + 16;                    // A row for acc1 fragments
    const int i0 = (m0 >> 2) + wm * 8 + q;     // h-row of frag0 cell
    const int i1 = i0 + 4;                     // h-row of frag1 cell

    // ---- one-time: stream this lane's weight fragments into registers ----
    bf16x8 rA0h[17], rA0l[17], rA1h[17], rA1l[17];
    {
        const unsigned short* p0h = Whi + (size_t)r0 * Kpad + kq;
        const unsigned short* p0l = Wlo + (size_t)r0 * Kpad + kq;
        const unsigned short* p1h = Whi + (size_t)r1 * Kpad + kq;
        const unsigned short* p1l = Wlo + (size_t)r1 * Kpad + kq;
#pragma unroll
        for (int kb = 0; kb < 17; ++kb) {
            rA0h[kb] = ld8(p0h + kb * 32);
            rA0l[kb] = ld8(p0l + kb * 32);
            rA1h[kb] = ld8(p1h + kb * 32);
            rA1l[kb] = ld8(p1l + kb * 32);
        }
    }

    float c0 = 0.f, c1 = 0.f;
    const f32x4 binit0 = { bg[i0], bi[i0], bf_[i0], bo[i0] };
    const f32x4 binit1 = { bg[i1], bi[i1], bf_[i1], bo[i1] };

    for (int t = 0; t < Tdim; ++t) {
        const unsigned short* Rh = (t & 1) ? H1hi : H0hi;
        unsigned short* Wh = (t & 1) ? H0hi : H1hi;
        const unsigned short* Bp = Rh + (size_t)colc * Hdim + kq;
        const unsigned short* XbH = Xhi + ((size_t)t * Bdim + colc) * 32 + kq;
        const unsigned short* XbL = Xlo + ((size_t)t * Bdim + colc) * 32 + kq;

        // ---- phase 1: issue ALL B(h-hi) loads of this step (batched) ----
        u64 rbh[16][2];
#pragma unroll
        for (int kb = 0; kb < 16; ++kb) {
            const u64* p0 = (const u64*)(Bp + kb * 32);
            rbh[kb][0] = ldA(p0);
            rbh[kb][1] = ldA(p0 + 1);
        }
        bf16x8 xh = ld8(XbH), xl = ld8(XbL);   // x: read-only, ordinary cached

        // ---- phase 2: MFMA, all-register operands ----
        f32x4 acc0 = binit0, acc1 = binit1;
#pragma unroll
        for (int kb = 0; kb < 16; ++kb) {
            bf16x8 bh = pack2(rbh[kb][0], rbh[kb][1]);
            acc0 = mfma16(rA0h[kb], bh, acc0);
            acc1 = mfma16(rA1h[kb], bh, acc1);
            acc0 = mfma16(rA0l[kb], bh, acc0);
            acc1 = mfma16(rA1l[kb], bh, acc1);
        }
        {   // x tail (k block 16): x keeps hi+lo
            acc0 = mfma16(rA0h[16], xh, acc0);
            acc1 = mfma16(rA1h[16], xh, acc1);
            acc0 = mfma16(rA0h[16], xl, acc0);
            acc1 = mfma16(rA1h[16], xl, acc1);
            acc0 = mfma16(rA0l[16], xh, acc0);
            acc1 = mfma16(rA1l[16], xh, acc1);
        }

        {   // frag0 cell update (h-row i0, col colc)
            float g = tanh_fast(acc0[0]), ii = sigm(acc0[1]);
            float f = sigm(acc0[2]),      o  = sigm(acc0[3]);
            c0 = g * ii + c0 * f;
            float h = tanh_fast(c0) * o;
            size_t idx = (size_t)colc * Hdim + i0;
            stH(Wh + idx, f2bf(h));
            if (t == Tdim - 1) Hf32[idx] = h;
        }
        {   // frag1 cell update (h-row i1, col colc)
            float g = tanh_fast(acc1[0]), ii = sigm(acc1[1]);
            float f = sigm(acc1[2]),      o  = sigm(acc1[3]);
            c1 = g * ii + c1 * f;
            float h = tanh_fast(c1) * o;
            size_t idx = (size_t)colc * Hdim + i1;
            stH(Wh + idx, f2bf(h));
            if (t == Tdim - 1) Hf32[idx] = h;
        }

        // ---- column-group barrier (R9-proven): flags + wave0 parallel poll ----
        asm volatile("s_waitcnt vmcnt(0)" ::: "memory");  // h stores acked at L3
        __syncthreads();                                  // all waves drained
        if (wv == 0) {
            if (lane == 0)
                __hip_atomic_store(myflag, (unsigned)(t + 1),
                                   __ATOMIC_RELAXED, __HIP_MEMORY_SCOPE_AGENT);
            const unsigned tgt = (unsigned)(t + 1);
            bool ok = lane >= 32;                         // lanes 0..31 poll WG lane
            int guard = 1 << 16;  // bounded: pathological case -> no hang
            while (!ok && --guard) {
                unsigned v = __hip_atomic_load(pollp, __ATOMIC_RELAXED,
                                               __HIP_MEMORY_SCOPE_AGENT);
                ok = (v >= tgt);
                if (!ok) __builtin_amdgcn_s_sleep(1);     // pace the fabric traffic
            }
        }
        __syncthreads();
        asm volatile("" ::: "memory");   // no B-load hoisting above the barrier
    }
}

// ---------- output: logits + softmax, one block per batch element ----------
__global__ __launch_bounds__(64) void k_out(
    const float* __restrict__ Hf32, const float* __restrict__ w_out,
    const float* __restrict__ b_out, float* __restrict__ out) {
    int b = blockIdx.x;
    int lane = threadIdx.x;
    const f32x4* h4 = (const f32x4*)(Hf32 + (size_t)b * 512);
    f32x4 h0 = h4[lane * 2], h1 = h4[lane * 2 + 1];
    float acc[10];
#pragma unroll
    for (int c = 0; c < 10; ++c) {
        const f32x4* w4 = (const f32x4*)(w_out + c * 512);
        f32x4 w0 = w4[lane * 2], w1 = w4[lane * 2 + 1];
        acc[c] = h0[0]*w0[0] + h0[1]*w0[1] + h0[2]*w0[2] + h0[3]*w0[3]
               + h1[0]*w1[0] + h1[1]*w1[1] + h1[2]*w1[2] + h1[3]*w1[3];
    }
#pragma unroll
    for (int s = 32; s >= 1; s >>= 1)
#pragma unroll
        for (int c = 0; c < 10; ++c) acc[c] += __shfl_xor(acc[c], s, 64);
    if (lane == 0) {
        float logit[10];
#pragma unroll
        for (int c = 0; c < 10; ++c) logit[c] = acc[c] + b_out[c];
        float m = logit[0];
#pragma unroll
        for (int c = 1; c < 10; ++c) m = fmaxf(m, logit[c]);
        float e[10], sum = 0.f;
#pragma unroll
        for (int c = 0; c < 10; ++c) { e[c] = __expf(logit[c] - m); sum += e[c]; }
        float inv = 1.f / sum;
#pragma unroll
        for (int c = 0; c < 10; ++c) out[b * 10 + c] = e[c] * inv;
    }
}

extern "C" void kernel_launch(void* const* d_in, const int* in_sizes, int n_in,
                              void* d_out, int out_size, void* d_ws, size_t ws_size,
                              hipStream_t stream) {
    const float* x    = (const float*)d_in[0];
    const float* w_gx = (const float*)d_in[1];
    const float* w_gh = (const float*)d_in[2];
    const float* b_g  = (const float*)d_in[3];
    const float* w_ix = (const float*)d_in[4];
    const float* w_ih = (const float*)d_in[5];
    const float* b_i  = (const float*)d_in[6];
    const float* w_fx = (const float*)d_in[7];
    const float* w_fh = (const float*)d_in[8];
    const float* b_f  = (const float*)d_in[9];
    const float* w_ox = (const float*)d_in[10];
    const float* w_oh = (const float*)d_in[11];
    const float* b_o  = (const float*)d_in[12];
    const float* w_out = (const float*)d_in[13];
    const float* b_out = (const float*)d_in[14];
    float* out = (float*)d_out;

    char* ws = (char*)d_ws;
    size_t off = 0;
    auto alloc = [&](size_t bytes) { void* p = ws + off; off += (bytes + 255) & ~255ull; return p; };
    // flags | H0hi contiguous -> one zeroing kernel
    unsigned*       flags = (unsigned*)alloc(16384);      // 256 WG-flags, 64B apart
    unsigned short* H0hi  = (unsigned short*)alloc((size_t)Bdim * 512 * 2);
    unsigned short* H1hi  = (unsigned short*)alloc((size_t)Bdim * 512 * 2);
    float*          Hf32  = (float*)alloc((size_t)Bdim * 512 * 4);
    unsigned short* Whi   = (unsigned short*)alloc(2048ull * Kpad * 2);
    unsigned short* Wlo   = (unsigned short*)alloc(2048ull * Kpad * 2);
    unsigned short* Xhi   = (unsigned short*)alloc((size_t)Tdim * Bdim * 32 * 2);
    unsigned short* Xlo   = (unsigned short*)alloc((size_t)Tdim * Bdim * 32 * 2);
    (void)ws_size; (void)in_sizes; (void)n_in; (void)out_size;

    k_prep_w<<<(2048 * Kpad + 255) / 256, 256, 0, stream>>>(
        w_gh, w_ih, w_fh, w_oh, w_gx, w_ix, w_fx, w_ox, Whi, Wlo);
    k_prep_x<<<(Tdim * Bdim * 32 + 255) / 256, 256, 0, stream>>>(x, Xhi, Xlo);
    // zero flags+H0hi: 16384 + 262144 B = 69,632 floats = 272 blocks
    k_zero<<<272, 256, 0, stream>>>((float*)flags);

    hipFuncSetAttribute((const void*)k_persist,
                        hipFuncAttributeMaxDynamicSharedMemorySize, LDS_BYTES);
    k_persist<<<dim3(256), dim3(256), LDS_BYTES, stream>>>(
        Whi, Wlo, Xhi, Xlo, H0hi, H1hi,
        Hf32, b_g, b_i, b_f, b_o, flags);

    k_out<<<256, 64, 0, stream>>>(Hf32, w_out, b_out, out);
}

// Round 14
// 1350.888 us; speedup vs baseline: 1.2300x; 1.2300x over previous
//
#include <hip/hip_runtime.h>

// LSTM H=512, B=256, T=256, D_IN=10, C=10. fp32 in/out.
// R14: R9 fabric + two traffic fixes with derived-conflict-free layouts:
// (1) phase-split LDS B-panel (16 cols, PROW=520 -> optimal 8-cy b128 access)
//     kills the 2x intra-WG B duplication: global B 16->8 MB/step. Phase-B
//     loads issue before MFMA-A (latency hidden under compute).
// (2) compact h layout [rg][col][row%16]: WG stores 1KB contiguous ->
//     WRITE_SIZE 4x down, shorter store-ack in the serial chain.
// Wave mapping = R12's verified one (wave w rows w*16..+15; lane cells
// (i0,col0),(i0,col0+16)). Barrier/fabric byte-identical to R9.

#define Hdim 512
#define Bdim 256
#define Tdim 256
#define Kpad 544          // 512 (h) + 32 (x: 10 real + 22 zero)
#define LROW 552          // weight LDS row stride (shorts), R9-proven
#define PROW 520          // panel LDS col stride (shorts): optimal bank map
#define LDS_BYTES ((64 * LROW * 2 + 16 * PROW) * 2)   // 157,952 B -> 1 WG/CU

typedef __bf16 bf16x8 __attribute__((ext_vector_type(8)));
typedef float f32x4 __attribute__((ext_vector_type(4)));
typedef unsigned long long u64;

__device__ __forceinline__ unsigned short f2bf(float f) {
    union { float f; unsigned u; } x; x.f = f;
    unsigned r = x.u + 0x7FFFu + ((x.u >> 16) & 1u);
    return (unsigned short)(r >> 16);
}
__device__ __forceinline__ float bf2f(unsigned short h) {
    union { unsigned u; float f; } x; x.u = ((unsigned)h) << 16;
    return x.f;
}
__device__ __forceinline__ bf16x8 ld8(const unsigned short* p) {
    return *reinterpret_cast<const bf16x8*>(p);
}
__device__ __forceinline__ u64 ldA(const u64* p) {   // coherent 8B load (L3)
    return __hip_atomic_load(p, __ATOMIC_RELAXED, __HIP_MEMORY_SCOPE_AGENT);
}
// write-through 2B store (agent scope -> lands at coherence point)
__device__ __forceinline__ void stH(unsigned short* p, unsigned short v) {
    __hip_atomic_store(p, v, __ATOMIC_RELAXED, __HIP_MEMORY_SCOPE_AGENT);
}
__device__ __forceinline__ f32x4 mfma16(bf16x8 a, bf16x8 b, f32x4 c) {
    return __builtin_amdgcn_mfma_f32_16x16x32_bf16(a, b, c, 0, 0, 0);
}
__device__ __forceinline__ bf16x8 pack2(u64 a, u64 b) {
    union { u64 q[2]; bf16x8 v; } u; u.q[0] = a; u.q[1] = b; return u.v;
}
__device__ __forceinline__ float sigm(float x) { return 1.f / (1.f + __expf(-x)); }
__device__ __forceinline__ float tanh_fast(float x) {
    return 2.f / (1.f + __expf(-2.f * x)) - 1.f;
}

// ---------- prep: stacked gate weights -> bf16 hi/lo, row = 4*i + gate ----------
__global__ void k_prep_w(const float* __restrict__ w_gh, const float* __restrict__ w_ih,
                         const float* __restrict__ w_fh, const float* __restrict__ w_oh,
                         const float* __restrict__ w_gx, const float* __restrict__ w_ix,
                         const float* __restrict__ w_fx, const float* __restrict__ w_ox,
                         unsigned short* __restrict__ Whi, unsigned short* __restrict__ Wlo) {
    int idx = blockIdx.x * 256 + threadIdx.x;
    if (idx >= 2048 * Kpad) return;
    int rw = idx / Kpad;
    int k  = idx % Kpad;
    int gate = rw & 3;
    int i = rw >> 2;
    float v = 0.f;
    if (k < 512) {
        const float* wh = (gate == 0) ? w_gh : (gate == 1) ? w_ih : (gate == 2) ? w_fh : w_oh;
        v = wh[i * 512 + k];
    } else if (k < 522) {
        const float* wx = (gate == 0) ? w_gx : (gate == 1) ? w_ix : (gate == 2) ? w_fx : w_ox;
        v = wx[i * 10 + (k - 512)];
    }
    unsigned short hi = f2bf(v);
    unsigned short lo = f2bf(v - bf2f(hi));
    Whi[idx] = hi;
    Wlo[idx] = lo;
}

// ---------- prep: x -> Xhi/Xlo [t][b][32] ----------
__global__ void k_prep_x(const float* __restrict__ x,
                         unsigned short* __restrict__ Xhi, unsigned short* __restrict__ Xlo) {
    int idx = blockIdx.x * 256 + threadIdx.x;
    if (idx >= Tdim * Bdim * 32) return;
    int j = idx & 31;
    int b = (idx >> 5) & 255;
    int t = idx >> 13;
    float v = 0.f;
    if (j < 10) v = x[(b * Tdim + t) * 10 + j];
    unsigned short hi = f2bf(v);
    unsigned short lo = f2bf(v - bf2f(hi));
    Xhi[idx] = hi;
    Xlo[idx] = lo;
}

__global__ void k_zero(float* __restrict__ p) {
    p[blockIdx.x * 256 + threadIdx.x] = 0.f;
}

// ---------- persistent LSTM ----------
// 256 WGs x 256 thr. WG: 64 stacked rows x 32 cols. Wave w: rows w*16..+15.
// h buffers are COMPACT: Hc[(rg*256 + col)*16 + row%16], rg = row/16.
__global__ __launch_bounds__(256, 1) void k_persist(
    const unsigned short* __restrict__ Whi, const unsigned short* __restrict__ Wlo,
    const unsigned short* __restrict__ Xhi, const unsigned short* __restrict__ Xlo,
    unsigned short* H0c, unsigned short* H1c,
    float* __restrict__ Hf32,
    const float* __restrict__ bg, const float* __restrict__ bi,
    const float* __restrict__ bf_, const float* __restrict__ bo,
    unsigned* flags) {
    extern __shared__ unsigned short lds[];
    unsigned short* Lhi = lds;                    // [64][LROW]
    unsigned short* Llo = lds + 64 * LROW;        // [64][LROW]
    unsigned short* Pp  = lds + 64 * LROW * 2;    // [16][PROW] panel

    const int bid = blockIdx.x;
    const int rg  = bid >> 3;                  // row-group id (0..31)
    const int m0  = rg * 64;                   // stacked-row tile base
    const int ct  = bid & 7;                   // column-group id
    const int bn0 = ct * 32;
    const int tid = threadIdx.x;
    const int lane = tid & 63;
    const int w  = tid >> 6;                   // wave id: rows w*16..w*16+15
    const int lr = lane & 15, q = lane >> 4;

    // flags: one 64B line per WG
    unsigned* myflag = flags + (((ct << 5) + rg) << 4);
    unsigned* pollp  = flags + (((ct << 5) + (lane & 31)) << 4);

    // panel staging role: thread (cl = tid>>4, e = tid&15) loads rg-chunks
    // e and e+16 of column (bn0 [+16] + cl): 2 x 32B per phase.
    const int cl = tid >> 4;
    const int e  = tid & 15;

    // one-time weight staging global -> LDS (R9 layout)
    for (int it = tid; it < 64 * 68; it += 256) {
        int r = it / 68, c8 = (it % 68) * 8;
        *(bf16x8*)&Lhi[r * LROW + c8] = ld8(Whi + (size_t)(m0 + r) * Kpad + c8);
        *(bf16x8*)&Llo[r * LROW + c8] = ld8(Wlo + (size_t)(m0 + r) * Kpad + c8);
    }
    __syncthreads();

    const int kq = q * 8;
    const int col0 = bn0 + lr;                 // acc0 cell column (phase A)
    const int col1 = col0 + 16;                // acc1 cell column (phase B)
    const int i0 = rg * 16 + w * 4 + q;        // h-row of both cells
    const int r16 = w * 4 + q;                 // row%16 for compact store

    float c0 = 0.f, c1 = 0.f;
    const f32x4 binit = { bg[i0], bi[i0], bf_[i0], bo[i0] };

    const unsigned short* Ah = &Lhi[(w * 16 + lr) * LROW + kq];
    const unsigned short* Al = &Llo[(w * 16 + lr) * LROW + kq];
    const unsigned short* Bl = &Pp[lr * PROW + kq];
    unsigned short* Pd0 = &Pp[cl * PROW + e * 16];        // chunk rg=e
    unsigned short* Pd1 = &Pp[cl * PROW + e * 16 + 256];  // chunk rg=e+16

    for (int t = 0; t < Tdim; ++t) {
        const unsigned short* Rh = (t & 1) ? H1c : H0c;
        unsigned short* Whc = (t & 1) ? H0c : H1c;

        // ---- phase A staging loads (cols bn0..bn0+15), batched ----
        u64 a0[4], a1[4];
        {
            const u64* s0 = (const u64*)(Rh + ((size_t)e * 256 + bn0 + cl) * 16);
            const u64* s1 = (const u64*)(Rh + ((size_t)(e + 16) * 256 + bn0 + cl) * 16);
#pragma unroll
            for (int v = 0; v < 4; ++v) a0[v] = ldA(s0 + v);
#pragma unroll
            for (int v = 0; v < 4; ++v) a1[v] = ldA(s1 + v);
        }
        // write panel A (16B stores, optimal bank map)
        *(bf16x8*)(Pd0)     = pack2(a0[0], a0[1]);
        *(bf16x8*)(Pd0 + 8) = pack2(a0[2], a0[3]);
        *(bf16x8*)(Pd1)     = pack2(a1[0], a1[1]);
        *(bf16x8*)(Pd1 + 8) = pack2(a1[2], a1[3]);
        __syncthreads();                       // panel A ready

        // ---- issue phase B staging loads (cols bn0+16..+31) ----
        u64 b0[4], b1[4];
        {
            const u64* s0 = (const u64*)(Rh + ((size_t)e * 256 + bn0 + 16 + cl) * 16);
            const u64* s1 = (const u64*)(Rh + ((size_t)(e + 16) * 256 + bn0 + 16 + cl) * 16);
#pragma unroll
            for (int v = 0; v < 4; ++v) b0[v] = ldA(s0 + v);
#pragma unroll
            for (int v = 0; v < 4; ++v) b1[v] = ldA(s1 + v);
        }
        // x fragments (read-only, cached)
        const unsigned short* xb  = Xhi + ((size_t)t * Bdim) * 32;
        const unsigned short* xbl = Xlo + ((size_t)t * Bdim) * 32;
        bf16x8 xh0 = ld8(xb + col0 * 32 + kq), xl0 = ld8(xbl + col0 * 32 + kq);
        bf16x8 xh1 = ld8(xb + col1 * 32 + kq), xl1 = ld8(xbl + col1 * 32 + kq);

        // ---- MFMA phase A (cols 0-15) -> acc0 ----
        f32x4 acc0 = binit, acc1 = binit;
#pragma unroll
        for (int kb = 0; kb < 16; ++kb) {
            const int k = kb * 32;
            bf16x8 ah = ld8(Ah + k), al = ld8(Al + k);
            bf16x8 bh = ld8(Bl + k);
            acc0 = mfma16(ah, bh, acc0);
            acc0 = mfma16(al, bh, acc0);
        }
        {   // x tail acc0
            bf16x8 ah = ld8(Ah + 512), al = ld8(Al + 512);
            acc0 = mfma16(ah, xh0, acc0);
            acc0 = mfma16(ah, xl0, acc0);
            acc0 = mfma16(al, xh0, acc0);
        }
        __syncthreads();                       // panel A consumed

        // write panel B
        *(bf16x8*)(Pd0)     = pack2(b0[0], b0[1]);
        *(bf16x8*)(Pd0 + 8) = pack2(b0[2], b0[3]);
        *(bf16x8*)(Pd1)     = pack2(b1[0], b1[1]);
        *(bf16x8*)(Pd1 + 8) = pack2(b1[2], b1[3]);
        __syncthreads();                       // panel B ready

        // ---- MFMA phase B (cols 16-31) -> acc1 ----
#pragma unroll
        for (int kb = 0; kb < 16; ++kb) {
            const int k = kb * 32;
            bf16x8 ah = ld8(Ah + k), al = ld8(Al + k);
            bf16x8 bh = ld8(Bl + k);
            acc1 = mfma16(ah, bh, acc1);
            acc1 = mfma16(al, bh, acc1);
        }
        {   // x tail acc1
            bf16x8 ah = ld8(Ah + 512), al = ld8(Al + 512);
            acc1 = mfma16(ah, xh1, acc1);
            acc1 = mfma16(ah, xl1, acc1);
            acc1 = mfma16(al, xh1, acc1);
        }

        {   // cell (i0, col0): compact store
            float g = tanh_fast(acc0[0]), ii = sigm(acc0[1]);
            float f = sigm(acc0[2]),      o  = sigm(acc0[3]);
            c0 = g * ii + c0 * f;
            float h = tanh_fast(c0) * o;
            stH(Whc + ((size_t)rg * 256 + col0) * 16 + r16, f2bf(h));
            if (t == Tdim - 1) Hf32[(size_t)col0 * Hdim + i0] = h;
        }
        {   // cell (i0, col1): compact store
            float g = tanh_fast(acc1[0]), ii = sigm(acc1[1]);
            float f = sigm(acc1[2]),      o  = sigm(acc1[3]);
            c1 = g * ii + c1 * f;
            float h = tanh_fast(c1) * o;
            stH(Whc + ((size_t)rg * 256 + col1) * 16 + r16, f2bf(h));
            if (t == Tdim - 1) Hf32[(size_t)col1 * Hdim + i0] = h;
        }

        // ---- column-group barrier (R9-proven) ----
        asm volatile("s_waitcnt vmcnt(0)" ::: "memory");  // h stores acked
        __syncthreads();                                  // all waves drained
        if (w == 0) {
            if (lane == 0)
                __hip_atomic_store(myflag, (unsigned)(t + 1),
                                   __ATOMIC_RELAXED, __HIP_MEMORY_SCOPE_AGENT);
            const unsigned tgt = (unsigned)(t + 1);
            bool ok = lane >= 32;                         // lanes 0..31 poll WG lane
            int guard = 1 << 16;  // bounded: pathological case -> no hang
            while (!ok && --guard) {
                unsigned v = __hip_atomic_load(pollp, __ATOMIC_RELAXED,
                                               __HIP_MEMORY_SCOPE_AGENT);
                ok = (v >= tgt);
                if (!ok) __builtin_amdgcn_s_sleep(1);     // pace the fabric
            }
        }
        __syncthreads();
        asm volatile("" ::: "memory");   // no staging-load hoist above barrier
    }
}

// ---------- output: logits + softmax, one block per batch element ----------
__global__ __launch_bounds__(64) void k_out(
    const float* __restrict__ Hf32, const float* __restrict__ w_out,
    const float* __restrict__ b_out, float* __restrict__ out) {
    int b = blockIdx.x;
    int lane = threadIdx.x;
    const f32x4* h4 = (const f32x4*)(Hf32 + (size_t)b * 512);
    f32x4 h0 = h4[lane * 2], h1 = h4[lane * 2 + 1];
    float acc[10];
#pragma unroll
    for (int c = 0; c < 10; ++c) {
        const f32x4* w4 = (const f32x4*)(w_out + c * 512);
        f32x4 w0 = w4[lane * 2], w1 = w4[lane * 2 + 1];
        acc[c] = h0[0]*w0[0] + h0[1]*w0[1] + h0[2]*w0[2] + h0[3]*w0[3]
               + h1[0]*w1[0] + h1[1]*w1[1] + h1[2]*w1[2] + h1[3]*w1[3];
    }
#pragma unroll
    for (int s = 32; s >= 1; s >>= 1)
#pragma unroll
        for (int c = 0; c < 10; ++c) acc[c] += __shfl_xor(acc[c], s, 64);
    if (lane == 0) {
        float logit[10];
#pragma unroll
        for (int c = 0; c < 10; ++c) logit[c] = acc[c] + b_out[c];
        float m = logit[0];
#pragma unroll
        for (int c = 1; c < 10; ++c) m = fmaxf(m, logit[c]);
        float e[10], sum = 0.f;
#pragma unroll
        for (int c = 0; c < 10; ++c) { e[c] = __expf(logit[c] - m); sum += e[c]; }
        float inv = 1.f / sum;
#pragma unroll
        for (int c = 0; c < 10; ++c) out[b * 10 + c] = e[c] * inv;
    }
}

extern "C" void kernel_launch(void* const* d_in, const int* in_sizes, int n_in,
                              void* d_out, int out_size, void* d_ws, size_t ws_size,
                              hipStream_t stream) {
    const float* x    = (const float*)d_in[0];
    const float* w_gx = (const float*)d_in[1];
    const float* w_gh = (const float*)d_in[2];
    const float* b_g  = (const float*)d_in[3];
    const float* w_ix = (const float*)d_in[4];
    const float* w_ih = (const float*)d_in[5];
    const float* b_i  = (const float*)d_in[6];
    const float* w_fx = (const float*)d_in[7];
    const float* w_fh = (const float*)d_in[8];
    const float* b_f  = (const float*)d_in[9];
    const float* w_ox = (const float*)d_in[10];
    const float* w_oh = (const float*)d_in[11];
    const float* b_o  = (const float*)d_in[12];
    const float* w_out = (const float*)d_in[13];
    const float* b_out = (const float*)d_in[14];
    float* out = (float*)d_out;

    char* ws = (char*)d_ws;
    size_t off = 0;
    auto alloc = [&](size_t bytes) { void* p = ws + off; off += (bytes + 255) & ~255ull; return p; };
    // flags | H0c contiguous -> one zeroing kernel
    unsigned*       flags = (unsigned*)alloc(16384);      // 256 WG-flags, 64B apart
    unsigned short* H0c   = (unsigned short*)alloc((size_t)Bdim * 512 * 2);
    unsigned short* H1c   = (unsigned short*)alloc((size_t)Bdim * 512 * 2);
    float*          Hf32  = (float*)alloc((size_t)Bdim * 512 * 4);
    unsigned short* Whi   = (unsigned short*)alloc(2048ull * Kpad * 2);
    unsigned short* Wlo   = (unsigned short*)alloc(2048ull * Kpad * 2);
    unsigned short* Xhi   = (unsigned short*)alloc((size_t)Tdim * Bdim * 32 * 2);
    unsigned short* Xlo   = (unsigned short*)alloc((size_t)Tdim * Bdim * 32 * 2);
    (void)ws_size; (void)in_sizes; (void)n_in; (void)out_size;

    k_prep_w<<<(2048 * Kpad + 255) / 256, 256, 0, stream>>>(
        w_gh, w_ih, w_fh, w_oh, w_gx, w_ix, w_fx, w_ox, Whi, Wlo);
    k_prep_x<<<(Tdim * Bdim * 32 + 255) / 256, 256, 0, stream>>>(x, Xhi, Xlo);
    // zero flags+H0c: 16384 + 262144 B = 69,632 floats = 272 blocks
    k_zero<<<272, 256, 0, stream>>>((float*)flags);

    hipFuncSetAttribute((const void*)k_persist,
                        hipFuncAttributeMaxDynamicSharedMemorySize, LDS_BYTES);
    k_persist<<<dim3(256), dim3(256), LDS_BYTES, stream>>>(
        Whi, Wlo, Xhi, Xlo, H0c, H1c,
        Hf32, b_g, b_i, b_f, b_o, flags);

    k_out<<<256, 64, 0, stream>>>(Hf32, w_out, b_out, out);
}

// Round 16
// 1350.031 us; speedup vs baseline: 1.2308x; 1.0006x over previous
//
#include <hip/hip_runtime.h>

// LSTM H=512, B=256, T=256, D_IN=10, C=10. fp32 in/out.
// R16 = R15 resubmission (R15 hit the known-dead container 'crisp-trim-mellow-
// exam' - 4th "first message" connect failure; kernel never ran).
// R14 + coalesced h-stores via LDS bounce (single-variable change vs R14).
// h layout [((ct*32+rg)*32+col_local)*16+r16] -> WG output = contiguous 1KB;
// epilogue bounces h through 1KB LDS, then 256 threads store one dword each
// (256B/wave contiguous write-through; full 32B sector utilization).
// Panel staging reads the same layout at 32B/thread. Barrier/fabric/numerics
// byte-identical to R14. All loops bounded - cannot wedge the GPU.

#define Hdim 512
#define Bdim 256
#define Tdim 256
#define Kpad 544          // 512 (h) + 32 (x: 10 real + 22 zero)
#define LROW 552          // weight LDS row stride (shorts)
#define PROW 520          // panel LDS col stride (shorts)
#define LDS_BYTES ((64 * LROW * 2 + 16 * PROW + 512) * 2)   // 158,976 B -> 1 WG/CU

typedef __bf16 bf16x8 __attribute__((ext_vector_type(8)));
typedef float f32x4 __attribute__((ext_vector_type(4)));
typedef unsigned long long u64;

__device__ __forceinline__ unsigned short f2bf(float f) {
    union { float f; unsigned u; } x; x.f = f;
    unsigned r = x.u + 0x7FFFu + ((x.u >> 16) & 1u);
    return (unsigned short)(r >> 16);
}
__device__ __forceinline__ float bf2f(unsigned short h) {
    union { unsigned u; float f; } x; x.u = ((unsigned)h) << 16;
    return x.f;
}
__device__ __forceinline__ bf16x8 ld8(const unsigned short* p) {
    return *reinterpret_cast<const bf16x8*>(p);
}
__device__ __forceinline__ u64 ldA(const u64* p) {   // coherent 8B load (L3)
    return __hip_atomic_load(p, __ATOMIC_RELAXED, __HIP_MEMORY_SCOPE_AGENT);
}
// write-through 4B store (agent scope -> lands at coherence point)
__device__ __forceinline__ void stH32(unsigned* p, unsigned v) {
    __hip_atomic_store(p, v, __ATOMIC_RELAXED, __HIP_MEMORY_SCOPE_AGENT);
}
__device__ __forceinline__ f32x4 mfma16(bf16x8 a, bf16x8 b, f32x4 c) {
    return __builtin_amdgcn_mfma_f32_16x16x32_bf16(a, b, c, 0, 0, 0);
}
__device__ __forceinline__ bf16x8 pack2(u64 a, u64 b) {
    union { u64 q[2]; bf16x8 v; } u; u.q[0] = a; u.q[1] = b; return u.v;
}
__device__ __forceinline__ float sigm(float x) { return 1.f / (1.f + __expf(-x)); }
__device__ __forceinline__ float tanh_fast(float x) {
    return 2.f / (1.f + __expf(-2.f * x)) - 1.f;
}

// ---------- prep: stacked gate weights -> bf16 hi/lo, row = 4*i + gate ----------
__global__ void k_prep_w(const float* __restrict__ w_gh, const float* __restrict__ w_ih,
                         const float* __restrict__ w_fh, const float* __restrict__ w_oh,
                         const float* __restrict__ w_gx, const float* __restrict__ w_ix,
                         const float* __restrict__ w_fx, const float* __restrict__ w_ox,
                         unsigned short* __restrict__ Whi, unsigned short* __restrict__ Wlo) {
    int idx = blockIdx.x * 256 + threadIdx.x;
    if (idx >= 2048 * Kpad) return;
    int rw = idx / Kpad;
    int k  = idx % Kpad;
    int gate = rw & 3;
    int i = rw >> 2;
    float v = 0.f;
    if (k < 512) {
        const float* wh = (gate == 0) ? w_gh : (gate == 1) ? w_ih : (gate == 2) ? w_fh : w_oh;
        v = wh[i * 512 + k];
    } else if (k < 522) {
        const float* wx = (gate == 0) ? w_gx : (gate == 1) ? w_ix : (gate == 2) ? w_fx : w_ox;
        v = wx[i * 10 + (k - 512)];
    }
    unsigned short hi = f2bf(v);
    unsigned short lo = f2bf(v - bf2f(hi));
    Whi[idx] = hi;
    Wlo[idx] = lo;
}

// ---------- prep: x -> Xhi/Xlo [t][b][32] ----------
__global__ void k_prep_x(const float* __restrict__ x,
                         unsigned short* __restrict__ Xhi, unsigned short* __restrict__ Xlo) {
    int idx = blockIdx.x * 256 + threadIdx.x;
    if (idx >= Tdim * Bdim * 32) return;
    int j = idx & 31;
    int b = (idx >> 5) & 255;
    int t = idx >> 13;
    float v = 0.f;
    if (j < 10) v = x[(b * Tdim + t) * 10 + j];
    unsigned short hi = f2bf(v);
    unsigned short lo = f2bf(v - bf2f(hi));
    Xhi[idx] = hi;
    Xlo[idx] = lo;
}

__global__ void k_zero(float* __restrict__ p) {
    p[blockIdx.x * 256 + threadIdx.x] = 0.f;
}

// ---------- persistent LSTM ----------
// 256 WGs x 256 thr. WG: 64 stacked rows x 32 cols. Wave w: rows w*16..+15.
// h layout: Hc[((ct*32+rg)*32 + col_local)*16 + r16] -> 1KB/WG contiguous.
__global__ __launch_bounds__(256, 1) void k_persist(
    const unsigned short* __restrict__ Whi, const unsigned short* __restrict__ Wlo,
    const unsigned short* __restrict__ Xhi, const unsigned short* __restrict__ Xlo,
    unsigned short* H0c, unsigned short* H1c,
    float* __restrict__ Hf32,
    const float* __restrict__ bg, const float* __restrict__ bi,
    const float* __restrict__ bf_, const float* __restrict__ bo,
    unsigned* flags) {
    extern __shared__ unsigned short lds[];
    unsigned short* Lhi = lds;                       // [64][LROW]
    unsigned short* Llo = lds + 64 * LROW;           // [64][LROW]
    unsigned short* Pp  = lds + 64 * LROW * 2;       // [16][PROW] panel
    unsigned short* Ho  = Pp + 16 * PROW;            // [32][16] h-out bounce

    const int bid = blockIdx.x;
    const int rg  = bid >> 3;                  // row-group id (0..31)
    const int m0  = rg * 64;                   // stacked-row tile base
    const int ct  = bid & 7;                   // column-group id
    const int bn0 = ct * 32;
    const int tid = threadIdx.x;
    const int lane = tid & 63;
    const int w  = tid >> 6;                   // wave id: rows w*16..w*16+15
    const int lr = lane & 15, q = lane >> 4;

    // flags: one 64B line per WG
    unsigned* myflag = flags + (((ct << 5) + rg) << 4);
    unsigned* pollp  = flags + (((ct << 5) + (lane & 31)) << 4);

    // panel staging role: thread (cl = tid>>4, e = tid&15)
    const int cl = tid >> 4;
    const int e  = tid & 15;

    // one-time weight staging global -> LDS
    for (int it = tid; it < 64 * 68; it += 256) {
        int r = it / 68, c8 = (it % 68) * 8;
        *(bf16x8*)&Lhi[r * LROW + c8] = ld8(Whi + (size_t)(m0 + r) * Kpad + c8);
        *(bf16x8*)&Llo[r * LROW + c8] = ld8(Wlo + (size_t)(m0 + r) * Kpad + c8);
    }
    __syncthreads();

    const int kq = q * 8;
    const int col0 = bn0 + lr;                 // acc0 cell column (phase A)
    const int col1 = col0 + 16;                // acc1 cell column (phase B)
    const int i0 = rg * 16 + w * 4 + q;        // h-row of both cells
    const int r16 = w * 4 + q;                 // row%16

    float c0 = 0.f, c1 = 0.f;
    const f32x4 binit = { bg[i0], bi[i0], bf_[i0], bo[i0] };

    const unsigned short* Ah = &Lhi[(w * 16 + lr) * LROW + kq];
    const unsigned short* Al = &Llo[(w * 16 + lr) * LROW + kq];
    const unsigned short* Bl = &Pp[lr * PROW + kq];
    unsigned short* Pd0 = &Pp[cl * PROW + e * 16];        // rows of rg=e
    unsigned short* Pd1 = &Pp[cl * PROW + e * 16 + 256];  // rows of rg=e+16

    // global h block base (compact layout)
    const size_t myblk = ((size_t)ct * 32 + rg) * 512;    // this WG's 1KB block

    for (int t = 0; t < Tdim; ++t) {
        const unsigned short* Rh = (t & 1) ? H1c : H0c;
        unsigned short* Whc = (t & 1) ? H0c : H1c;

        // ---- phase A staging loads (cols cl 0..15 of this ct), batched ----
        u64 a0[4], a1[4];
        {
            const u64* s0 = (const u64*)(Rh + (((size_t)ct * 32 + e) * 32 + cl) * 16);
            const u64* s1 = (const u64*)(Rh + (((size_t)ct * 32 + e + 16) * 32 + cl) * 16);
#pragma unroll
            for (int v = 0; v < 4; ++v) a0[v] = ldA(s0 + v);
#pragma unroll
            for (int v = 0; v < 4; ++v) a1[v] = ldA(s1 + v);
        }
        // write panel A
        *(bf16x8*)(Pd0)     = pack2(a0[0], a0[1]);
        *(bf16x8*)(Pd0 + 8) = pack2(a0[2], a0[3]);
        *(bf16x8*)(Pd1)     = pack2(a1[0], a1[1]);
        *(bf16x8*)(Pd1 + 8) = pack2(a1[2], a1[3]);
        __syncthreads();                       // panel A ready

        // ---- issue phase B staging loads (cols cl+16) ----
        u64 b0[4], b1[4];
        {
            const u64* s0 = (const u64*)(Rh + (((size_t)ct * 32 + e) * 32 + 16 + cl) * 16);
            const u64* s1 = (const u64*)(Rh + (((size_t)ct * 32 + e + 16) * 32 + 16 + cl) * 16);
#pragma unroll
            for (int v = 0; v < 4; ++v) b0[v] = ldA(s0 + v);
#pragma unroll
            for (int v = 0; v < 4; ++v) b1[v] = ldA(s1 + v);
        }
        // x fragments (read-only, cached)
        const unsigned short* xb  = Xhi + ((size_t)t * Bdim) * 32;
        const unsigned short* xbl = Xlo + ((size_t)t * Bdim) * 32;
        bf16x8 xh0 = ld8(xb + col0 * 32 + kq), xl0 = ld8(xbl + col0 * 32 + kq);
        bf16x8 xh1 = ld8(xb + col1 * 32 + kq), xl1 = ld8(xbl + col1 * 32 + kq);

        // ---- MFMA phase A (cols 0-15) -> acc0 ----
        f32x4 acc0 = binit, acc1 = binit;
#pragma unroll
        for (int kb = 0; kb < 16; ++kb) {
            const int k = kb * 32;
            bf16x8 ah = ld8(Ah + k), al = ld8(Al + k);
            bf16x8 bh = ld8(Bl + k);
            acc0 = mfma16(ah, bh, acc0);
            acc0 = mfma16(al, bh, acc0);
        }
        {   // x tail acc0
            bf16x8 ah = ld8(Ah + 512), al = ld8(Al + 512);
            acc0 = mfma16(ah, xh0, acc0);
            acc0 = mfma16(ah, xl0, acc0);
            acc0 = mfma16(al, xh0, acc0);
        }
        __syncthreads();                       // panel A consumed

        // write panel B
        *(bf16x8*)(Pd0)     = pack2(b0[0], b0[1]);
        *(bf16x8*)(Pd0 + 8) = pack2(b0[2], b0[3]);
        *(bf16x8*)(Pd1)     = pack2(b1[0], b1[1]);
        *(bf16x8*)(Pd1 + 8) = pack2(b1[2], b1[3]);
        __syncthreads();                       // panel B ready

        // ---- MFMA phase B (cols 16-31) -> acc1 ----
#pragma unroll
        for (int kb = 0; kb < 16; ++kb) {
            const int k = kb * 32;
            bf16x8 ah = ld8(Ah + k), al = ld8(Al + k);
            bf16x8 bh = ld8(Bl + k);
            acc1 = mfma16(ah, bh, acc1);
            acc1 = mfma16(al, bh, acc1);
        }
        {   // x tail acc1
            bf16x8 ah = ld8(Ah + 512), al = ld8(Al + 512);
            acc1 = mfma16(ah, xh1, acc1);
            acc1 = mfma16(ah, xl1, acc1);
            acc1 = mfma16(al, xh1, acc1);
        }

        {   // cell (i0, col0) -> LDS bounce
            float g = tanh_fast(acc0[0]), ii = sigm(acc0[1]);
            float f = sigm(acc0[2]),      o  = sigm(acc0[3]);
            c0 = g * ii + c0 * f;
            float h = tanh_fast(c0) * o;
            Ho[lr * 16 + r16] = f2bf(h);
            if (t == Tdim - 1) Hf32[(size_t)col0 * Hdim + i0] = h;
        }
        {   // cell (i0, col1) -> LDS bounce
            float g = tanh_fast(acc1[0]), ii = sigm(acc1[1]);
            float f = sigm(acc1[2]),      o  = sigm(acc1[3]);
            c1 = g * ii + c1 * f;
            float h = tanh_fast(c1) * o;
            Ho[(16 + lr) * 16 + r16] = f2bf(h);
            if (t == Tdim - 1) Hf32[(size_t)col1 * Hdim + i0] = h;
        }
        __syncthreads();                       // Ho complete

        // ---- coalesced write-through store: 1 dword/thread, 1KB/WG ----
        stH32((unsigned*)(Whc + myblk) + tid, *(const unsigned*)&Ho[tid * 2]);

        // ---- column-group barrier (R9-proven) ----
        asm volatile("s_waitcnt vmcnt(0)" ::: "memory");  // h stores acked
        __syncthreads();                                  // all waves drained
        if (w == 0) {
            if (lane == 0)
                __hip_atomic_store(myflag, (unsigned)(t + 1),
                                   __ATOMIC_RELAXED, __HIP_MEMORY_SCOPE_AGENT);
            const unsigned tgt = (unsigned)(t + 1);
            bool ok = lane >= 32;                         // lanes 0..31 poll WG lane
            int guard = 1 << 16;  // bounded: pathological case -> no hang
            while (!ok && --guard) {
                unsigned v = __hip_atomic_load(pollp, __ATOMIC_RELAXED,
                                               __HIP_MEMORY_SCOPE_AGENT);
                ok = (v >= tgt);
                if (!ok) __builtin_amdgcn_s_sleep(1);     // pace the fabric
            }
        }
        __syncthreads();
        asm volatile("" ::: "memory");   // no staging-load hoist above barrier
    }
}

// ---------- output: logits + softmax, one block per batch element ----------
__global__ __launch_bounds__(64) void k_out(
    const float* __restrict__ Hf32, const float* __restrict__ w_out,
    const float* __restrict__ b_out, float* __restrict__ out) {
    int b = blockIdx.x;
    int lane = threadIdx.x;
    const f32x4* h4 = (const f32x4*)(Hf32 + (size_t)b * 512);
    f32x4 h0 = h4[lane * 2], h1 = h4[lane * 2 + 1];
    float acc[10];
#pragma unroll
    for (int c = 0; c < 10; ++c) {
        const f32x4* w4 = (const f32x4*)(w_out + c * 512);
        f32x4 w0 = w4[lane * 2], w1 = w4[lane * 2 + 1];
        acc[c] = h0[0]*w0[0] + h0[1]*w0[1] + h0[2]*w0[2] + h0[3]*w0[3]
               + h1[0]*w1[0] + h1[1]*w1[1] + h1[2]*w1[2] + h1[3]*w1[3];
    }
#pragma unroll
    for (int s = 32; s >= 1; s >>= 1)
#pragma unroll
        for (int c = 0; c < 10; ++c) acc[c] += __shfl_xor(acc[c], s, 64);
    if (lane == 0) {
        float logit[10];
#pragma unroll
        for (int c = 0; c < 10; ++c) logit[c] = acc[c] + b_out[c];
        float m = logit[0];
#pragma unroll
        for (int c = 1; c < 10; ++c) m = fmaxf(m, logit[c]);
        float e[10], sum = 0.f;
#pragma unroll
        for (int c = 0; c < 10; ++c) { e[c] = __expf(logit[c] - m); sum += e[c]; }
        float inv = 1.f / sum;
#pragma unroll
        for (int c = 0; c < 10; ++c) out[b * 10 + c] = e[c] * inv;
    }
}

extern "C" void kernel_launch(void* const* d_in, const int* in_sizes, int n_in,
                              void* d_out, int out_size, void* d_ws, size_t ws_size,
                              hipStream_t stream) {
    const float* x    = (const float*)d_in[0];
    const float* w_gx = (const float*)d_in[1];
    const float* w_gh = (const float*)d_in[2];
    const float* b_g  = (const float*)d_in[3];
    const float* w_ix = (const float*)d_in[4];
    const float* w_ih = (const float*)d_in[5];
    const float* b_i  = (const float*)d_in[6];
    const float* w_fx = (const float*)d_in[7];
    const float* w_fh = (const float*)d_in[8];
    const float* b_f  = (const float*)d_in[9];
    const float* w_ox = (const float*)d_in[10];
    const float* w_oh = (const float*)d_in[11];
    const float* b_o  = (const float*)d_in[12];
    const float* w_out = (const float*)d_in[13];
    const float* b_out = (const float*)d_in[14];
    float* out = (float*)d_out;

    char* ws = (char*)d_ws;
    size_t off = 0;
    auto alloc = [&](size_t bytes) { void* p = ws + off; off += (bytes + 255) & ~255ull; return p; };
    // flags | H0c contiguous -> one zeroing kernel
    unsigned*       flags = (unsigned*)alloc(16384);      // 256 WG-flags, 64B apart
    unsigned short* H0c   = (unsigned short*)alloc((size_t)Bdim * 512 * 2);
    unsigned short* H1c   = (unsigned short*)alloc((size_t)Bdim * 512 * 2);
    float*          Hf32  = (float*)alloc((size_t)Bdim * 512 * 4);
    unsigned short* Whi   = (unsigned short*)alloc(2048ull * Kpad * 2);
    unsigned short* Wlo   = (unsigned short*)alloc(2048ull * Kpad * 2);
    unsigned short* Xhi   = (unsigned short*)alloc((size_t)Tdim * Bdim * 32 * 2);
    unsigned short* Xlo   = (unsigned short*)alloc((size_t)Tdim * Bdim * 32 * 2);
    (void)ws_size; (void)in_sizes; (void)n_in; (void)out_size;

    k_prep_w<<<(2048 * Kpad + 255) / 256, 256, 0, stream>>>(
        w_gh, w_ih, w_fh, w_oh, w_gx, w_ix, w_fx, w_ox, Whi, Wlo);
    k_prep_x<<<(Tdim * Bdim * 32 + 255) / 256, 256, 0, stream>>>(x, Xhi, Xlo);
    // zero flags+H0c: 16384 + 262144 B = 278,528 B = 69,632 floats = 272 blocks
    k_zero<<<272, 256, 0, stream>>>((float*)flags);

    hipFuncSetAttribute((const void*)k_persist,
                        hipFuncAttributeMaxDynamicSharedMemorySize, LDS_BYTES);
    k_persist<<<dim3(256), dim3(256), LDS_BYTES, stream>>>(
        Whi, Wlo, Xhi, Xlo, H0c, H1c,
        Hf32, b_g, b_i, b_f, b_o, flags);

    k_out<<<256, 64, 0, stream>>>(Hf32, w_out, b_out, out);
}

// Round 18
// 1131.009 us; speedup vs baseline: 1.4691x; 1.1937x over previous
//
#include <hip/hip_runtime.h>

// LSTM H=512, B=256, T=256, D_IN=10, C=10. fp32 in/out.
// R18 = R17 (split-flag A/B pipelining) + RACE FIXES, resubmitted after the
// known-dead container ate R17 (5th "first message" failure; never ran).
// Race fixes vs R17: flagA now posts AFTER S5 (barrier's per-wave vmcnt drain
// covers wave1's storeA); new S6 barrier before flagB post (waves 2-3's
// storeB provably drained). Correctness is structural, not timing-dependent.
// Design: flagA posted mid-step (h cols 0-15), flagB end-of-step (cols 16-31);
// consumer polls hit first-try in steady state; stageB hides under MFMA-A,
// storeA ack under MFMA-B. Only stageA's load hop remains exposed.

#define Hdim 512
#define Bdim 256
#define Tdim 256
#define Kpad 544          // 512 (h) + 32 (x: 10 real + 22 zero)
#define LROW 552          // weight LDS row stride (shorts)
#define PROW 520          // panel LDS col stride (shorts)
#define LDS_BYTES ((64 * LROW * 2 + 16 * PROW + 512) * 2)   // 158,976 B -> 1 WG/CU

typedef __bf16 bf16x8 __attribute__((ext_vector_type(8)));
typedef float f32x4 __attribute__((ext_vector_type(4)));
typedef unsigned long long u64;

__device__ __forceinline__ unsigned short f2bf(float f) {
    union { float f; unsigned u; } x; x.f = f;
    unsigned r = x.u + 0x7FFFu + ((x.u >> 16) & 1u);
    return (unsigned short)(r >> 16);
}
__device__ __forceinline__ float bf2f(unsigned short h) {
    union { unsigned u; float f; } x; x.u = ((unsigned)h) << 16;
    return x.f;
}
__device__ __forceinline__ bf16x8 ld8(const unsigned short* p) {
    return *reinterpret_cast<const bf16x8*>(p);
}
__device__ __forceinline__ u64 ldA(const u64* p) {   // coherent 8B load (L3)
    return __hip_atomic_load(p, __ATOMIC_RELAXED, __HIP_MEMORY_SCOPE_AGENT);
}
// write-through 4B store (agent scope -> lands at coherence point)
__device__ __forceinline__ void stH32(unsigned* p, unsigned v) {
    __hip_atomic_store(p, v, __ATOMIC_RELAXED, __HIP_MEMORY_SCOPE_AGENT);
}
__device__ __forceinline__ f32x4 mfma16(bf16x8 a, bf16x8 b, f32x4 c) {
    return __builtin_amdgcn_mfma_f32_16x16x32_bf16(a, b, c, 0, 0, 0);
}
__device__ __forceinline__ bf16x8 pack2(u64 a, u64 b) {
    union { u64 q[2]; bf16x8 v; } u; u.q[0] = a; u.q[1] = b; return u.v;
}
__device__ __forceinline__ float sigm(float x) { return 1.f / (1.f + __expf(-x)); }
__device__ __forceinline__ float tanh_fast(float x) {
    return 2.f / (1.f + __expf(-2.f * x)) - 1.f;
}
// poll helper: wave0 lanes 0-31, first check sleepless, bounded
__device__ __forceinline__ void pollFlags(const unsigned* pollp, unsigned tgt, int lane) {
    bool ok = lane >= 32;
    if (!ok) {
        unsigned v = __hip_atomic_load(pollp, __ATOMIC_RELAXED, __HIP_MEMORY_SCOPE_AGENT);
        ok = (v >= tgt);
    }
    int guard = 1 << 16;
    while (!ok && --guard) {
        __builtin_amdgcn_s_sleep(1);
        unsigned v = __hip_atomic_load(pollp, __ATOMIC_RELAXED, __HIP_MEMORY_SCOPE_AGENT);
        ok = (v >= tgt);
    }
}

// ---------- prep: stacked gate weights -> bf16 hi/lo, row = 4*i + gate ----------
__global__ void k_prep_w(const float* __restrict__ w_gh, const float* __restrict__ w_ih,
                         const float* __restrict__ w_fh, const float* __restrict__ w_oh,
                         const float* __restrict__ w_gx, const float* __restrict__ w_ix,
                         const float* __restrict__ w_fx, const float* __restrict__ w_ox,
                         unsigned short* __restrict__ Whi, unsigned short* __restrict__ Wlo) {
    int idx = blockIdx.x * 256 + threadIdx.x;
    if (idx >= 2048 * Kpad) return;
    int rw = idx / Kpad;
    int k  = idx % Kpad;
    int gate = rw & 3;
    int i = rw >> 2;
    float v = 0.f;
    if (k < 512) {
        const float* wh = (gate == 0) ? w_gh : (gate == 1) ? w_ih : (gate == 2) ? w_fh : w_oh;
        v = wh[i * 512 + k];
    } else if (k < 522) {
        const float* wx = (gate == 0) ? w_gx : (gate == 1) ? w_ix : (gate == 2) ? w_fx : w_ox;
        v = wx[i * 10 + (k - 512)];
    }
    unsigned short hi = f2bf(v);
    unsigned short lo = f2bf(v - bf2f(hi));
    Whi[idx] = hi;
    Wlo[idx] = lo;
}

// ---------- prep: x -> Xhi/Xlo [t][b][32] ----------
__global__ void k_prep_x(const float* __restrict__ x,
                         unsigned short* __restrict__ Xhi, unsigned short* __restrict__ Xlo) {
    int idx = blockIdx.x * 256 + threadIdx.x;
    if (idx >= Tdim * Bdim * 32) return;
    int j = idx & 31;
    int b = (idx >> 5) & 255;
    int t = idx >> 13;
    float v = 0.f;
    if (j < 10) v = x[(b * Tdim + t) * 10 + j];
    unsigned short hi = f2bf(v);
    unsigned short lo = f2bf(v - bf2f(hi));
    Xhi[idx] = hi;
    Xlo[idx] = lo;
}

__global__ void k_zero(float* __restrict__ p) {
    p[blockIdx.x * 256 + threadIdx.x] = 0.f;
}

// ---------- persistent LSTM ----------
// 256 WGs x 256 thr. WG: 64 stacked rows x 32 cols. Wave w: rows w*16..+15.
// h layout: Hc[((ct*32+rg)*32 + col_local)*16 + r16] -> 1KB/WG contiguous.
// Flags: flagsA (cols 0-15 stored), flagsB (cols 16-31 stored), 64B lines.
__global__ __launch_bounds__(256, 1) void k_persist(
    const unsigned short* __restrict__ Whi, const unsigned short* __restrict__ Wlo,
    const unsigned short* __restrict__ Xhi, const unsigned short* __restrict__ Xlo,
    unsigned short* H0c, unsigned short* H1c,
    float* __restrict__ Hf32,
    const float* __restrict__ bg, const float* __restrict__ bi,
    const float* __restrict__ bf_, const float* __restrict__ bo,
    unsigned* flags) {
    extern __shared__ unsigned short lds[];
    unsigned short* Lhi = lds;                       // [64][LROW]
    unsigned short* Llo = lds + 64 * LROW;           // [64][LROW]
    unsigned short* Pp  = lds + 64 * LROW * 2;       // [16][PROW] panel
    unsigned short* Ho  = Pp + 16 * PROW;            // [32][16] h-out bounce

    const int bid = blockIdx.x;
    const int rg  = bid >> 3;                  // row-group id (0..31)
    const int m0  = rg * 64;                   // stacked-row tile base
    const int ct  = bid & 7;                   // column-group id
    const int bn0 = ct * 32;
    const int tid = threadIdx.x;
    const int lane = tid & 63;
    const int w  = tid >> 6;                   // wave id: rows w*16..w*16+15
    const int lr = lane & 15, q = lane >> 4;

    // flags: flagsA = flags[0..4095], flagsB = flags[4096..8191] (uints)
    unsigned* flagsA = flags;
    unsigned* flagsB = flags + 4096;
    unsigned* myflagA = flagsA + (((ct << 5) + rg) << 4);
    unsigned* myflagB = flagsB + (((ct << 5) + rg) << 4);
    const unsigned* pollpA = flagsA + (((ct << 5) + (lane & 31)) << 4);
    const unsigned* pollpB = flagsB + (((ct << 5) + (lane & 31)) << 4);

    // panel staging role: thread (cl = tid>>4, e = tid&15)
    const int cl = tid >> 4;
    const int e  = tid & 15;

    // one-time weight staging global -> LDS
    for (int it = tid; it < 64 * 68; it += 256) {
        int r = it / 68, c8 = (it % 68) * 8;
        *(bf16x8*)&Lhi[r * LROW + c8] = ld8(Whi + (size_t)(m0 + r) * Kpad + c8);
        *(bf16x8*)&Llo[r * LROW + c8] = ld8(Wlo + (size_t)(m0 + r) * Kpad + c8);
    }
    __syncthreads();

    const int kq = q * 8;
    const int col0 = bn0 + lr;                 // acc0 cell column (phase A)
    const int col1 = col0 + 16;                // acc1 cell column (phase B)
    const int i0 = rg * 16 + w * 4 + q;        // h-row of both cells
    const int r16 = w * 4 + q;                 // row%16

    float c0 = 0.f, c1 = 0.f;
    const f32x4 binit = { bg[i0], bi[i0], bf_[i0], bo[i0] };

    const unsigned short* Ah = &Lhi[(w * 16 + lr) * LROW + kq];
    const unsigned short* Al = &Llo[(w * 16 + lr) * LROW + kq];
    const unsigned short* Bl = &Pp[lr * PROW + kq];
    unsigned short* Pd0 = &Pp[cl * PROW + e * 16];        // rows of rg=e
    unsigned short* Pd1 = &Pp[cl * PROW + e * 16 + 256];  // rows of rg=e+16

    // global h block base (compact layout)
    const size_t myblk = ((size_t)ct * 32 + rg) * 512;    // this WG's 1KB block

    for (int t = 0; t < Tdim; ++t) {
        const unsigned short* Rh = (t & 1) ? H1c : H0c;
        unsigned short* Whc = (t & 1) ? H0c : H1c;
        const unsigned tgt = (unsigned)t;      // h(t-1) availability generation

        // ---- gate A: h(t-1) cols 0-15 stored (first-try hit in steady state)
        if (w == 0) pollFlags(pollpA, tgt, lane);
        __syncthreads();                       // S0
        asm volatile("" ::: "memory");

        // ---- stageA loads (cols cl of this ct), batched ----
        u64 a0[4], a1[4];
        {
            const u64* s0 = (const u64*)(Rh + (((size_t)ct * 32 + e) * 32 + cl) * 16);
            const u64* s1 = (const u64*)(Rh + (((size_t)ct * 32 + e + 16) * 32 + cl) * 16);
#pragma unroll
            for (int v = 0; v < 4; ++v) a0[v] = ldA(s0 + v);
#pragma unroll
            for (int v = 0; v < 4; ++v) a1[v] = ldA(s1 + v);
        }
        // x fragments (read-only, cached)
        const unsigned short* xb  = Xhi + ((size_t)t * Bdim) * 32;
        const unsigned short* xbl = Xlo + ((size_t)t * Bdim) * 32;
        bf16x8 xh0 = ld8(xb + col0 * 32 + kq), xl0 = ld8(xbl + col0 * 32 + kq);
        bf16x8 xh1 = ld8(xb + col1 * 32 + kq), xl1 = ld8(xbl + col1 * 32 + kq);

        // ---- gate B: h(t-1) cols 16-31 (polled under stageA latency) ----
        if (w == 0) pollFlags(pollpB, tgt, lane);
        __syncthreads();                       // S1
        asm volatile("" ::: "memory");

        // ---- stageB loads issue (latency hidden under MFMA-A) ----
        u64 b0[4], b1[4];
        {
            const u64* s0 = (const u64*)(Rh + (((size_t)ct * 32 + e) * 32 + 16 + cl) * 16);
            const u64* s1 = (const u64*)(Rh + (((size_t)ct * 32 + e + 16) * 32 + 16 + cl) * 16);
#pragma unroll
            for (int v = 0; v < 4; ++v) b0[v] = ldA(s0 + v);
#pragma unroll
            for (int v = 0; v < 4; ++v) b1[v] = ldA(s1 + v);
        }
        // write panel A (stageA data)
        *(bf16x8*)(Pd0)     = pack2(a0[0], a0[1]);
        *(bf16x8*)(Pd0 + 8) = pack2(a0[2], a0[3]);
        *(bf16x8*)(Pd1)     = pack2(a1[0], a1[1]);
        *(bf16x8*)(Pd1 + 8) = pack2(a1[2], a1[3]);
        __syncthreads();                       // S2: panel A ready

        // ---- MFMA phase A (cols 0-15) -> acc0 ----
        f32x4 acc0 = binit, acc1 = binit;
#pragma unroll
        for (int kb = 0; kb < 16; ++kb) {
            const int k = kb * 32;
            bf16x8 ah = ld8(Ah + k), al = ld8(Al + k);
            bf16x8 bh = ld8(Bl + k);
            acc0 = mfma16(ah, bh, acc0);
            acc0 = mfma16(al, bh, acc0);
        }
        {   // x tail acc0
            bf16x8 ah = ld8(Ah + 512), al = ld8(Al + 512);
            acc0 = mfma16(ah, xh0, acc0);
            acc0 = mfma16(ah, xl0, acc0);
            acc0 = mfma16(al, xh0, acc0);
        }
        {   // epilogue A: cell (i0, col0) -> Ho bytes [0,512)
            float g = tanh_fast(acc0[0]), ii = sigm(acc0[1]);
            float f = sigm(acc0[2]),      o  = sigm(acc0[3]);
            c0 = g * ii + c0 * f;
            float h = tanh_fast(c0) * o;
            Ho[lr * 16 + r16] = f2bf(h);
            if (t == Tdim - 1) Hf32[(size_t)col0 * Hdim + i0] = h;
        }
        __syncthreads();                       // S3: panel A consumed + Ho-A done

        // write panel B (stageB data)
        *(bf16x8*)(Pd0)     = pack2(b0[0], b0[1]);
        *(bf16x8*)(Pd0 + 8) = pack2(b0[2], b0[3]);
        *(bf16x8*)(Pd1)     = pack2(b1[0], b1[1]);
        *(bf16x8*)(Pd1 + 8) = pack2(b1[2], b1[3]);
        __syncthreads();                       // S4: panel B ready

        // ---- storeA (coalesced, bytes 0-511 of block) + MFMA-B overlap ----
        if (tid < 128)
            stH32((unsigned*)(Whc + myblk) + tid, *(const unsigned*)&Ho[tid * 2]);

        // ---- MFMA phase B (cols 16-31) -> acc1 (hides storeA latency) ----
#pragma unroll
        for (int kb = 0; kb < 16; ++kb) {
            const int k = kb * 32;
            bf16x8 ah = ld8(Ah + k), al = ld8(Al + k);
            bf16x8 bh = ld8(Bl + k);
            acc1 = mfma16(ah, bh, acc1);
            acc1 = mfma16(al, bh, acc1);
        }
        {   // x tail acc1
            bf16x8 ah = ld8(Ah + 512), al = ld8(Al + 512);
            acc1 = mfma16(ah, xh1, acc1);
            acc1 = mfma16(ah, xl1, acc1);
            acc1 = mfma16(al, xh1, acc1);
        }
        {   // epilogue B: cell (i0, col1) -> Ho bytes [512,1024)
            float g = tanh_fast(acc1[0]), ii = sigm(acc1[1]);
            float f = sigm(acc1[2]),      o  = sigm(acc1[3]);
            c1 = g * ii + c1 * f;
            float h = tanh_fast(c1) * o;
            Ho[(16 + lr) * 16 + r16] = f2bf(h);
            if (t == Tdim - 1) Hf32[(size_t)col1 * Hdim + i0] = h;
        }
        __syncthreads();     // S5: Ho-B done; ALL waves' storeA drained (barrier
                             // implies per-wave vmcnt(0) before s_barrier)
        // ---- post flagA: safe, storeA provably complete ----
        if (tid == 0)
            __hip_atomic_store(myflagA, (unsigned)(t + 1),
                               __ATOMIC_RELAXED, __HIP_MEMORY_SCOPE_AGENT);

        // ---- storeB (bytes 512-1023) ----
        if (tid >= 128)
            stH32((unsigned*)(Whc + myblk) + tid, *(const unsigned*)&Ho[tid * 2]);
        __syncthreads();     // S6: waves 2-3's storeB drained
        // ---- post flagB: safe ----
        if (tid == 0)
            __hip_atomic_store(myflagB, (unsigned)(t + 1),
                               __ATOMIC_RELAXED, __HIP_MEMORY_SCOPE_AGENT);
    }
}

// ---------- output: logits + softmax, one block per batch element ----------
__global__ __launch_bounds__(64) void k_out(
    const float* __restrict__ Hf32, const float* __restrict__ w_out,
    const float* __restrict__ b_out, float* __restrict__ out) {
    int b = blockIdx.x;
    int lane = threadIdx.x;
    const f32x4* h4 = (const f32x4*)(Hf32 + (size_t)b * 512);
    f32x4 h0 = h4[lane * 2], h1 = h4[lane * 2 + 1];
    float acc[10];
#pragma unroll
    for (int c = 0; c < 10; ++c) {
        const f32x4* w4 = (const f32x4*)(w_out + c * 512);
        f32x4 w0 = w4[lane * 2], w1 = w4[lane * 2 + 1];
        acc[c] = h0[0]*w0[0] + h0[1]*w0[1] + h0[2]*w0[2] + h0[3]*w0[3]
               + h1[0]*w1[0] + h1[1]*w1[1] + h1[2]*w1[2] + h1[3]*w1[3];
    }
#pragma unroll
    for (int s = 32; s >= 1; s >>= 1)
#pragma unroll
        for (int c = 0; c < 10; ++c) acc[c] += __shfl_xor(acc[c], s, 64);
    if (lane == 0) {
        float logit[10];
#pragma unroll
        for (int c = 0; c < 10; ++c) logit[c] = acc[c] + b_out[c];
        float m = logit[0];
#pragma unroll
        for (int c = 1; c < 10; ++c) m = fmaxf(m, logit[c]);
        float e[10], sum = 0.f;
#pragma unroll
        for (int c = 0; c < 10; ++c) { e[c] = __expf(logit[c] - m); sum += e[c]; }
        float inv = 1.f / sum;
#pragma unroll
        for (int c = 0; c < 10; ++c) out[b * 10 + c] = e[c] * inv;
    }
}

extern "C" void kernel_launch(void* const* d_in, const int* in_sizes, int n_in,
                              void* d_out, int out_size, void* d_ws, size_t ws_size,
                              hipStream_t stream) {
    const float* x    = (const float*)d_in[0];
    const float* w_gx = (const float*)d_in[1];
    const float* w_gh = (const float*)d_in[2];
    const float* b_g  = (const float*)d_in[3];
    const float* w_ix = (const float*)d_in[4];
    const float* w_ih = (const float*)d_in[5];
    const float* b_i  = (const float*)d_in[6];
    const float* w_fx = (const float*)d_in[7];
    const float* w_fh = (const float*)d_in[8];
    const float* b_f  = (const float*)d_in[9];
    const float* w_ox = (const float*)d_in[10];
    const float* w_oh = (const float*)d_in[11];
    const float* b_o  = (const float*)d_in[12];
    const float* w_out = (const float*)d_in[13];
    const float* b_out = (const float*)d_in[14];
    float* out = (float*)d_out;

    char* ws = (char*)d_ws;
    size_t off = 0;
    auto alloc = [&](size_t bytes) { void* p = ws + off; off += (bytes + 255) & ~255ull; return p; };
    // flags (A+B, 32KB) | H0c contiguous -> one zeroing kernel
    unsigned*       flags = (unsigned*)alloc(32768);      // 2 x 256 WG-flags, 64B apart
    unsigned short* H0c   = (unsigned short*)alloc((size_t)Bdim * 512 * 2);
    unsigned short* H1c   = (unsigned short*)alloc((size_t)Bdim * 512 * 2);
    float*          Hf32  = (float*)alloc((size_t)Bdim * 512 * 4);
    unsigned short* Whi   = (unsigned short*)alloc(2048ull * Kpad * 2);
    unsigned short* Wlo   = (unsigned short*)alloc(2048ull * Kpad * 2);
    unsigned short* Xhi   = (unsigned short*)alloc((size_t)Tdim * Bdim * 32 * 2);
    unsigned short* Xlo   = (unsigned short*)alloc((size_t)Tdim * Bdim * 32 * 2);
    (void)ws_size; (void)in_sizes; (void)n_in; (void)out_size;

    k_prep_w<<<(2048 * Kpad + 255) / 256, 256, 0, stream>>>(
        w_gh, w_ih, w_fh, w_oh, w_gx, w_ix, w_fx, w_ox, Whi, Wlo);
    k_prep_x<<<(Tdim * Bdim * 32 + 255) / 256, 256, 0, stream>>>(x, Xhi, Xlo);
    // zero flags(32KB)+H0c(256KB): 294,912 B = 73,728 floats = 288 blocks
    k_zero<<<288, 256, 0, stream>>>((float*)flags);

    hipFuncSetAttribute((const void*)k_persist,
                        hipFuncAttributeMaxDynamicSharedMemorySize, LDS_BYTES);
    k_persist<<<dim3(256), dim3(256), LDS_BYTES, stream>>>(
        Whi, Wlo, Xhi, Xlo, H0c, H1c,
        Hf32, b_g, b_i, b_f, b_o, flags);

    k_out<<<256, 64, 0, stream>>>(Hf32, w_out, b_out, out);
}